// Round 1
// baseline (324.861 us; speedup 1.0000x reference)
//
#include <hip/hip_runtime.h>
#include <math.h>

#define Hn 512
#define Nn 32
#define Bn 8
#define Ln 4096
#define Mfft 8192
#define NT 512            // threads per workgroup
#define KFSTRIDE 4097     // rfft bins per channel (L+1)

// ---------- small complex helpers ----------
__device__ __forceinline__ float2 cmul(float2 a, float2 b) {
    return make_float2(a.x * b.x - a.y * b.y, a.x * b.y + a.y * b.x);
}
__device__ __forceinline__ float2 cadd(float2 a, float2 b) { return make_float2(a.x + b.x, a.y + b.y); }
__device__ __forceinline__ float2 csub(float2 a, float2 b) { return make_float2(a.x - b.x, a.y - b.y); }

// LDS index swizzle: bijective involution, applied to EVERY LDS access so it is
// correctness-neutral; spreads the small-stride FFT passes across banks.
__device__ __forceinline__ int SW(int p) { return p ^ ((p >> 4) & 15); }
// 13-bit bit reversal (M = 8192)
__device__ __forceinline__ int BR(int k) { return (int)(__brev((unsigned)k) >> 19); }

// ---------- forward FFT: radix-2 DIF, two stages fused per LDS pass ----------
// natural-order input -> bit-reversed output (spectrum Z[k] lands at position BR(k))
__device__ void fft_dif(float2* Z, int tid) {
#pragma unroll
    for (int S1 = Mfft; S1 >= 8; S1 >>= 2) {
        const int m1 = S1 >> 1, m2 = S1 >> 2;
        __syncthreads();
#pragma unroll
        for (int t = 0; t < Mfft / 4 / NT; ++t) {
            int tau = tid + NT * t;
            int j = tau & (m2 - 1);
            int blk = tau / m2;              // m2 is compile-time (unrolled) -> shift
            int base = blk * S1 + j;
            float2 e0 = Z[SW(base)];
            float2 e1 = Z[SW(base + m2)];
            float2 e2 = Z[SW(base + m1)];
            float2 e3 = Z[SW(base + m1 + m2)];
            float ang = (-6.28318530717958647692f / (float)S1) * (float)j;
            float s, c;
            __sincosf(ang, &s, &c);
            float2 w1 = make_float2(c, s);
            float2 w2 = cmul(w1, w1);
            float2 w3 = cmul(w2, w1);
            float2 t02p = cadd(e0, e2), t02m = csub(e0, e2);
            float2 t13p = cadd(e1, e3), t13m = csub(e1, e3);
            float2 o0  = cadd(t02p, t13p);
            float2 om2 = cmul(csub(t02p, t13p), w2);
            float2 uu = make_float2(t02m.x + t13m.y, t02m.y - t13m.x); // t02m - i*t13m
            float2 vv = make_float2(t02m.x - t13m.y, t02m.y + t13m.x); // t02m + i*t13m
            float2 om1  = cmul(uu, w1);
            float2 om12 = cmul(vv, w3);
            Z[SW(base)]            = o0;
            Z[SW(base + m2)]       = om2;
            Z[SW(base + m1)]       = om1;
            Z[SW(base + m1 + m2)]  = om12;
        }
    }
    __syncthreads();
    // final trivial stage S=2 (twiddle = 1)
#pragma unroll
    for (int t = 0; t < Mfft / 2 / NT; ++t) {
        int tau = tid + NT * t;
        int p = 2 * tau;
        float2 a = Z[SW(p)], b = Z[SW(p + 1)];
        Z[SW(p)]     = cadd(a, b);
        Z[SW(p + 1)] = csub(a, b);
    }
    __syncthreads();
}

// ---------- inverse FFT: radix-2 DIT, two stages fused per LDS pass ----------
// bit-reversed input -> natural-order output.  NO 1/M scaling here (pre-folded into KF).
__device__ void fft_dit_inv(float2* Z, int tid) {
    __syncthreads();
    // trivial stage S=2 first
#pragma unroll
    for (int t = 0; t < Mfft / 2 / NT; ++t) {
        int tau = tid + NT * t;
        int p = 2 * tau;
        float2 a = Z[SW(p)], b = Z[SW(p + 1)];
        Z[SW(p)]     = cadd(a, b);
        Z[SW(p + 1)] = csub(a, b);
    }
#pragma unroll
    for (int S1 = 8; S1 <= Mfft; S1 <<= 2) {
        const int m1 = S1 >> 1, m2 = S1 >> 2;
        __syncthreads();
#pragma unroll
        for (int t = 0; t < Mfft / 4 / NT; ++t) {
            int tau = tid + NT * t;
            int j = tau & (m2 - 1);
            int blk = tau / m2;
            int base = blk * S1 + j;
            float2 e0 = Z[SW(base)];
            float2 e1 = Z[SW(base + m2)];
            float2 e2 = Z[SW(base + m1)];
            float2 e3 = Z[SW(base + m1 + m2)];
            float ang = (6.28318530717958647692f / (float)S1) * (float)j;
            float s, c;
            __sincosf(ang, &s, &c);
            float2 v2 = make_float2(c, s);
            float2 v1 = cmul(v2, v2);
            float2 t1 = cmul(e1, v1);
            float2 A0 = cadd(e0, t1), A1 = csub(e0, t1);
            float2 t3 = cmul(e3, v1);
            float2 A2 = cadd(e2, t3), A3 = csub(e2, t3);
            float2 t2 = cmul(A2, v2);
            float2 o0  = cadd(A0, t2);
            float2 om1 = csub(A0, t2);
            float2 t4 = cmul(A3, v2);
            float2 it4 = make_float2(-t4.y, t4.x);  // i * t4
            float2 om2  = cadd(A1, it4);
            float2 om12 = csub(A1, it4);
            Z[SW(base)]           = o0;
            Z[SW(base + m2)]      = om2;
            Z[SW(base + m1)]      = om1;
            Z[SW(base + m1 + m2)] = om12;
        }
    }
    __syncthreads();
}

// ---------- build time-domain bidirectional kernel for channel pair (2g, 2g+1) ----------
// Z[l]       = (k0_h0[l],  k0_h1[l])        l in [0, L)
// Z[8191-l]  = (k1_h0[l],  k1_h1[l])        (i.e. k1 reversed in the back half)
__device__ void gen_timedomain(float2* Z, int g, int tid,
                               const float* __restrict__ log_dt,
                               const float* __restrict__ lnA,
                               const float* __restrict__ A_im,
                               const float* __restrict__ B_ri,
                               const float* __restrict__ C_ri) {
    const double TWOPI = 6.283185307179586476925286766559;
#pragma unroll
    for (int hh = 0; hh < 2; ++hh) {
        int h = 2 * g + hh;
        float acc0[Ln / NT], acc1[Ln / NT];
#pragma unroll
        for (int i = 0; i < Ln / NT; ++i) { acc0[i] = 0.f; acc1[i] = 0.f; }
        float dt = __expf(log_dt[h]);
        for (int n = 0; n < Nn; ++n) {
            int idx = h * Nn + n;
            float are = -__expf(lnA[idx]);
            float aim = A_im[idx];
            float dre = dt * are;
            double dimr = fmod((double)dt * (double)aim, TWOPI);
            float s, c;
            // exp(dt*A)
            __sincosf((float)dimr, &s, &c);
            float er = __expf(dre);
            float2 ew = make_float2(er * c, er * s);
            // (exp(dt*A) - 1) / A
            float inv2 = 1.0f / (are * are + aim * aim);
            float2 num = make_float2(ew.x - 1.0f, ew.y);
            float2 disc = make_float2((num.x * are + num.y * aim) * inv2,
                                      (num.y * are - num.x * aim) * inv2);
            float2 Bc = make_float2(B_ri[idx * 2], B_ri[idx * 2 + 1]);
            float2 CB = cmul(Bc, disc);
            int i0 = (0 * Hn + h) * Nn + n, i1 = (1 * Hn + h) * Nn + n;
            float2 C0 = cmul(make_float2(C_ri[i0 * 2], C_ri[i0 * 2 + 1]), CB);
            float2 C1 = cmul(make_float2(C_ri[i1 * 2], C_ri[i1 * 2 + 1]), CB);
            C0.x *= 2.f; C0.y *= 2.f; C1.x *= 2.f; C1.y *= 2.f;
            // v = exp(dt*A*l0), l0 = tid ; step multiplier ws = exp(dt*A*NT)
            float e0m = __expf(dre * (float)tid);
            double a0 = fmod((double)tid * dimr, TWOPI);
            __sincosf((float)a0, &s, &c);
            float2 v = make_float2(e0m * c, e0m * s);
            float esm = __expf(dre * (float)NT);
            double as = fmod((double)NT * dimr, TWOPI);
            __sincosf((float)as, &s, &c);
            float2 wsv = make_float2(esm * c, esm * s);
#pragma unroll
            for (int i = 0; i < Ln / NT; ++i) {
                acc0[i] += C0.x * v.x - C0.y * v.y;   // 2*Re(C0 * w^l)
                acc1[i] += C1.x * v.x - C1.y * v.y;   // 2*Re(C1 * w^l)
                v = cmul(v, wsv);
            }
        }
#pragma unroll
        for (int i = 0; i < Ln / NT; ++i) {
            int l = tid + NT * i;
            ((float*)&Z[SW(l)])[hh]            = acc0[i];
            ((float*)&Z[SW(Mfft - 1 - l)])[hh] = acc1[i];
        }
    }
}

// ---------- kernel 1: precompute kernel spectra KF[h][k], k=0..4096, 1/M pre-folded ----------
__global__ __launch_bounds__(NT) void k_genkf(const float* __restrict__ log_dt,
                                              const float* __restrict__ lnA,
                                              const float* __restrict__ A_im,
                                              const float* __restrict__ B_ri,
                                              const float* __restrict__ C_ri,
                                              float2* __restrict__ KF) {
    __shared__ float2 Z[Mfft];
    int g = blockIdx.x, tid = threadIdx.x;
    gen_timedomain(Z, g, tid, log_dt, lnA, A_im, B_ri, C_ri);
    fft_dif(Z, tid);
    const float scale = 1.0f / (float)Mfft;   // irfft normalization, folded here
    for (int k = tid; k <= Ln; k += NT) {
        int pk  = SW(BR(k));
        int pmk = SW(BR((Mfft - k) & (Mfft - 1)));
        float2 zk = Z[pk], zmk = Z[pmk];
        float2 kf0 = make_float2(0.5f * (zk.x + zmk.x) * scale,  0.5f * (zk.y - zmk.y) * scale);
        float2 kf1 = make_float2(0.5f * (zk.y + zmk.y) * scale, -0.5f * (zk.x - zmk.x) * scale);
        KF[(size_t)(2 * g)     * KFSTRIDE + k] = kf0;
        KF[(size_t)(2 * g + 1) * KFSTRIDE + k] = kf1;
    }
}

// ---------- kernel 2: FFT convolution, two channels per workgroup ----------
__global__ __launch_bounds__(NT) void k_conv(const float* __restrict__ u,
                                             const float* __restrict__ D,
                                             const float2* __restrict__ KF,
                                             float* __restrict__ y) {
    __shared__ float2 Z[Mfft];
    int wg = blockIdx.x;
    int g = wg & (Hn / 2 - 1);
    int b = wg >> 8;
    int tid = threadIdx.x;
    int h0 = 2 * g, h1 = h0 + 1;
    const float* u0 = u + ((size_t)b * Hn + h0) * Ln;
    const float* u1 = u + ((size_t)b * Hn + h1) * Ln;
    float r0[Ln / NT], r1[Ln / NT];
#pragma unroll
    for (int i = 0; i < Ln / NT; ++i) {
        int l = tid + NT * i;
        r0[i] = u0[l];
        r1[i] = u1[l];
        Z[SW(l)]      = make_float2(r0[i], r1[i]);
        Z[SW(l + Ln)] = make_float2(0.f, 0.f);
    }
    fft_dif(Z, tid);
    // pointwise multiply in bit-reversed domain; each (k, M-k) pair owns its two slots
    for (int k = tid; k <= Ln; k += NT) {
        int pk  = SW(BR(k));
        int pmk = SW(BR((Mfft - k) & (Mfft - 1)));
        float2 zk = Z[pk], zmk = Z[pmk];
        float2 U0 = make_float2(0.5f * (zk.x + zmk.x),  0.5f * (zk.y - zmk.y));
        float2 U1 = make_float2(0.5f * (zk.y + zmk.y), -0.5f * (zk.x - zmk.x));
        float2 kf0 = KF[(size_t)h0 * KFSTRIDE + k];
        float2 kf1 = KF[(size_t)h1 * KFSTRIDE + k];
        float2 y0 = cmul(U0, kf0);
        float2 y1 = cmul(U1, kf1);
        Z[pk] = make_float2(y0.x - y1.y, y0.y + y1.x);          // Y[k] = y0 + i*y1
        if (k != 0 && k != Ln) {
            Z[pmk] = make_float2(y0.x + y1.y, y1.x - y0.y);     // Y[M-k] = conj(y0) + i*conj(y1)
        }
    }
    fft_dit_inv(Z, tid);
    float D0 = D[h0], D1 = D[h1];
    float* y0p = y + ((size_t)b * Hn + h0) * Ln;
    float* y1p = y + ((size_t)b * Hn + h1) * Ln;
#pragma unroll
    for (int i = 0; i < Ln / NT; ++i) {
        int l = tid + NT * i;
        float2 zl = Z[SW(l)];
        y0p[l] = zl.x + D0 * r0[i];
        y1p[l] = zl.y + D1 * r1[i];
    }
}

// ---------- fallback: fully fused (no workspace needed) ----------
__global__ __launch_bounds__(NT) void k_conv_fused(const float* __restrict__ u,
                                                   const float* __restrict__ log_dt,
                                                   const float* __restrict__ lnA,
                                                   const float* __restrict__ A_im,
                                                   const float* __restrict__ B_ri,
                                                   const float* __restrict__ C_ri,
                                                   const float* __restrict__ D,
                                                   float* __restrict__ y) {
    __shared__ float2 Z[Mfft];
    int wg = blockIdx.x;
    int g = wg & (Hn / 2 - 1);
    int b = wg >> 8;
    int tid = threadIdx.x;
    int h0 = 2 * g, h1 = h0 + 1;

    // kernel spectrum into registers
    gen_timedomain(Z, g, tid, log_dt, lnA, A_im, B_ri, C_ri);
    fft_dif(Z, tid);
    float2 kf0r[9], kf1r[9];
    const float scale = 1.0f / (float)Mfft;
#pragma unroll
    for (int i = 0; i < 9; ++i) {
        int k = tid + NT * i;
        if (k <= Ln) {
            int pk  = SW(BR(k));
            int pmk = SW(BR((Mfft - k) & (Mfft - 1)));
            float2 zk = Z[pk], zmk = Z[pmk];
            kf0r[i] = make_float2(0.5f * (zk.x + zmk.x) * scale,  0.5f * (zk.y - zmk.y) * scale);
            kf1r[i] = make_float2(0.5f * (zk.y + zmk.y) * scale, -0.5f * (zk.x - zmk.x) * scale);
        }
    }
    __syncthreads();   // everyone done reading kernel spectrum before overwriting Z

    const float* u0 = u + ((size_t)b * Hn + h0) * Ln;
    const float* u1 = u + ((size_t)b * Hn + h1) * Ln;
    float r0[Ln / NT], r1[Ln / NT];
#pragma unroll
    for (int i = 0; i < Ln / NT; ++i) {
        int l = tid + NT * i;
        r0[i] = u0[l];
        r1[i] = u1[l];
        Z[SW(l)]      = make_float2(r0[i], r1[i]);
        Z[SW(l + Ln)] = make_float2(0.f, 0.f);
    }
    fft_dif(Z, tid);
#pragma unroll
    for (int i = 0; i < 9; ++i) {
        int k = tid + NT * i;
        if (k <= Ln) {
            int pk  = SW(BR(k));
            int pmk = SW(BR((Mfft - k) & (Mfft - 1)));
            float2 zk = Z[pk], zmk = Z[pmk];
            float2 U0 = make_float2(0.5f * (zk.x + zmk.x),  0.5f * (zk.y - zmk.y));
            float2 U1 = make_float2(0.5f * (zk.y + zmk.y), -0.5f * (zk.x - zmk.x));
            float2 y0 = cmul(U0, kf0r[i]);
            float2 y1 = cmul(U1, kf1r[i]);
            Z[pk] = make_float2(y0.x - y1.y, y0.y + y1.x);
            if (k != 0 && k != Ln) {
                Z[pmk] = make_float2(y0.x + y1.y, y1.x - y0.y);
            }
        }
    }
    fft_dit_inv(Z, tid);
    float D0 = D[h0], D1 = D[h1];
    float* y0p = y + ((size_t)b * Hn + h0) * Ln;
    float* y1p = y + ((size_t)b * Hn + h1) * Ln;
#pragma unroll
    for (int i = 0; i < Ln / NT; ++i) {
        int l = tid + NT * i;
        float2 zl = Z[SW(l)];
        y0p[l] = zl.x + D0 * r0[i];
        y1p[l] = zl.y + D1 * r1[i];
    }
}

extern "C" void kernel_launch(void* const* d_in, const int* in_sizes, int n_in,
                              void* d_out, int out_size, void* d_ws, size_t ws_size,
                              hipStream_t stream) {
    const float* u      = (const float*)d_in[0];
    const float* log_dt = (const float*)d_in[1];
    const float* lnA    = (const float*)d_in[2];
    const float* A_im   = (const float*)d_in[3];
    const float* B_ri   = (const float*)d_in[4];
    const float* C_ri   = (const float*)d_in[5];
    const float* D      = (const float*)d_in[6];
    float* y = (float*)d_out;

    const size_t kf_bytes = (size_t)Hn * KFSTRIDE * sizeof(float2);  // ~16.8 MB
    if (ws_size >= kf_bytes) {
        float2* KF = (float2*)d_ws;
        k_genkf<<<Hn / 2, NT, 0, stream>>>(log_dt, lnA, A_im, B_ri, C_ri, KF);
        k_conv<<<Bn * Hn / 2, NT, 0, stream>>>(u, D, KF, y);
    } else {
        k_conv_fused<<<Bn * Hn / 2, NT, 0, stream>>>(u, log_dt, lnA, A_im, B_ri, C_ri, D, y);
    }
}

// Round 2
// 315.632 us; speedup vs baseline: 1.0292x; 1.0292x over previous
//
#include <hip/hip_runtime.h>
#include <math.h>

#define Hn 512
#define Nn 32
#define Bn 8
#define Ln 4096
#define Mfft 8192
#define NT 512
#define KFSTRIDE 4097

// ---------------- complex helpers ----------------
__device__ __forceinline__ float2 cmulf(float2 a, float2 b) {
    return make_float2(a.x * b.x - a.y * b.y, a.x * b.y + a.y * b.x);
}
__device__ __forceinline__ float2 caddf(float2 a, float2 b) { return make_float2(a.x + b.x, a.y + b.y); }
__device__ __forceinline__ float2 csubf(float2 a, float2 b) { return make_float2(a.x - b.x, a.y - b.y); }

// LDS swizzle at dword granularity: XOR low5 with block index -> every FFT stage
// lands at exactly 2 lanes/bank (free). Bijective involution, applied everywhere.
__device__ __forceinline__ int SWI(int a) { return a ^ ((a >> 5) & 31); }

__device__ __forceinline__ float2 ldz(const float* ZR, const float* ZI, int a) {
    int s = SWI(a);
    return make_float2(ZR[s], ZI[s]);
}
__device__ __forceinline__ void stz(float* ZR, float* ZI, int a, float2 v) {
    int s = SWI(a);
    ZR[s] = v.x;
    ZI[s] = v.y;
}

// storage address of frequency k after DIF stages 16 (stride512), 16 (32), 16 (2), 2 (1)
__device__ __forceinline__ int pmap(int k) {
    return ((k & 15) << 9) | (((k >> 4) & 15) << 5) | (((k >> 8) & 15) << 1) | (k >> 12);
}

// ---------------- in-register DFT-16 ----------------
template <int SGN>  // SGN=-1 forward (e^{-i}), +1 inverse
__device__ __forceinline__ void dft4(float2& a0, float2& a1, float2& a2, float2& a3) {
    float2 t0 = caddf(a0, a2), t1 = csubf(a0, a2);
    float2 t2 = caddf(a1, a3), t3 = csubf(a1, a3);
    float2 it3 = (SGN < 0) ? make_float2(t3.y, -t3.x) : make_float2(-t3.y, t3.x);
    a0 = caddf(t0, t2);
    a2 = csubf(t0, t2);
    a1 = caddf(t1, it3);
    a3 = csubf(t1, it3);
}

// input x[p] natural order; output: freq k lives at slot ((k&3)<<2)|(k>>2)
template <int SGN>
__device__ __forceinline__ void dft16(float2* x) {
    const float C1 = 0.92387953251128675613f, S1 = 0.38268343236508977173f, R2 = 0.70710678118654752440f;
    const float sg = (SGN < 0) ? -1.f : 1.f;
#pragma unroll
    for (int q = 0; q < 4; ++q) dft4<SGN>(x[q], x[q + 4], x[q + 8], x[q + 12]);
    const float2 w1 = make_float2(C1, sg * S1);
    const float2 w2 = make_float2(R2, sg * R2);
    const float2 w3 = make_float2(S1, sg * C1);
    const float2 w6 = make_float2(-R2, sg * R2);
    const float2 w9 = make_float2(-C1, -sg * S1);
    x[5] = cmulf(x[5], w1);
    x[9] = cmulf(x[9], w2);
    x[13] = cmulf(x[13], w3);
    x[6] = cmulf(x[6], w2);
    x[10] = make_float2(-sg * x[10].y, sg * x[10].x);  // * w16^4 = (0, sg)
    x[14] = cmulf(x[14], w6);
    x[7] = cmulf(x[7], w3);
    x[11] = cmulf(x[11], w6);
    x[15] = cmulf(x[15], w9);
#pragma unroll
    for (int a = 0; a < 4; ++a) dft4<SGN>(x[4 * a + 0], x[4 * a + 1], x[4 * a + 2], x[4 * a + 3]);
}

// ---------------- one radix-16 stage (gather stride, twiddle w^{r}, scatter same slots) ----------------
template <int SGN>
__device__ __forceinline__ void radix16_stage(float* ZR, float* ZI, int base, int stride, float tau) {
    float2 x[16];
#pragma unroll
    for (int p = 0; p < 16; ++p) x[p] = ldz(ZR, ZI, base + stride * p);

    float s, c;
    __sincosf(6.28318530717958647692f * tau, &s, &c);
    float2 w1 = make_float2(c, (SGN < 0) ? -s : s);
    float2 wr[16];
    wr[0] = make_float2(1.f, 0.f);
    wr[1] = w1;
    wr[2] = cmulf(w1, w1);
    wr[3] = cmulf(wr[2], w1);
    wr[4] = cmulf(wr[2], wr[2]);
    wr[5] = cmulf(wr[4], w1);
    wr[6] = cmulf(wr[4], wr[2]);
    wr[7] = cmulf(wr[4], wr[3]);
    wr[8] = cmulf(wr[4], wr[4]);
    wr[9] = cmulf(wr[8], w1);
    wr[10] = cmulf(wr[8], wr[2]);
    wr[11] = cmulf(wr[8], wr[3]);
    wr[12] = cmulf(wr[8], wr[4]);
    wr[13] = cmulf(wr[8], wr[5]);
    wr[14] = cmulf(wr[8], wr[6]);
    wr[15] = cmulf(wr[8], wr[7]);

    if (SGN < 0) {
        dft16<SGN>(x);
        stz(ZR, ZI, base, x[0]);
#pragma unroll
        for (int r = 1; r < 16; ++r) {
            int sl = ((r & 3) << 2) | (r >> 2);
            stz(ZR, ZI, base + stride * r, cmulf(x[sl], wr[r]));
        }
    } else {
#pragma unroll
        for (int r = 1; r < 16; ++r) x[r] = cmulf(x[r], wr[r]);
        dft16<SGN>(x);
#pragma unroll
        for (int n = 0; n < 16; ++n) {
            int sl = ((n & 3) << 2) | (n >> 2);
            stz(ZR, ZI, base + stride * n, x[sl]);
        }
    }
}

// ---------------- full 8192-pt FFTs, 4 LDS round-trips each ----------------
__device__ void fft_fwd(float* ZR, float* ZI, int tid) {
    __syncthreads();
    radix16_stage<-1>(ZR, ZI, tid, 512, (float)tid * (1.f / 8192.f));
    __syncthreads();
    radix16_stage<-1>(ZR, ZI, ((tid >> 5) << 9) + (tid & 31), 32, (float)(tid & 31) * (1.f / 512.f));
    __syncthreads();
    radix16_stage<-1>(ZR, ZI, ((tid >> 1) << 5) + (tid & 1), 2, (float)(tid & 1) * (1.f / 32.f));
    __syncthreads();
#pragma unroll
    for (int i = 0; i < 8; ++i) {
        int a = 2 * (tid + NT * i);
        float2 xx = ldz(ZR, ZI, a), yy = ldz(ZR, ZI, a + 1);
        stz(ZR, ZI, a, caddf(xx, yy));
        stz(ZR, ZI, a + 1, csubf(xx, yy));
    }
    __syncthreads();
}

__device__ void fft_inv(float* ZR, float* ZI, int tid) {
    __syncthreads();
#pragma unroll
    for (int i = 0; i < 8; ++i) {
        int a = 2 * (tid + NT * i);
        float2 xx = ldz(ZR, ZI, a), yy = ldz(ZR, ZI, a + 1);
        stz(ZR, ZI, a, caddf(xx, yy));
        stz(ZR, ZI, a + 1, csubf(xx, yy));
    }
    __syncthreads();
    radix16_stage<1>(ZR, ZI, ((tid >> 1) << 5) + (tid & 1), 2, (float)(tid & 1) * (1.f / 32.f));
    __syncthreads();
    radix16_stage<1>(ZR, ZI, ((tid >> 5) << 9) + (tid & 31), 32, (float)(tid & 31) * (1.f / 512.f));
    __syncthreads();
    radix16_stage<1>(ZR, ZI, tid, 512, (float)tid * (1.f / 8192.f));
    __syncthreads();
}

// ---------------- time-domain kernel generation into the two planes ----------------
// plane ZR: channel h0=2g ; plane ZI: channel h1=2g+1
// Z[l] = k0[l], Z[8191-l] = k1[l]   (per plane)
__device__ void gen_planes(float* ZR, float* ZI, int g, int tid,
                           const float* __restrict__ log_dt, const float* __restrict__ lnA,
                           const float* __restrict__ A_im, const float* __restrict__ B_ri,
                           const float* __restrict__ C_ri) {
#pragma unroll
    for (int hh = 0; hh < 2; ++hh) {
        int h = 2 * g + hh;
        float acc0[8], acc1[8];
#pragma unroll
        for (int i = 0; i < 8; ++i) { acc0[i] = 0.f; acc1[i] = 0.f; }
        float dt = __expf(log_dt[h]);
        for (int n = 0; n < Nn; ++n) {
            int idx = h * Nn + n;
            float are = -__expf(lnA[idx]);
            float aim = A_im[idx];
            float dre = dt * are;
            // rotation per step, in turns, hi/lo split so l*th12 is exact in f32
            double tau_d = (double)dt * (double)aim * 0.15915494309189533577;  // /2pi
            tau_d -= floor(tau_d);
            float th = (float)tau_d;
            float th12 = truncf(th * 4096.f) * (1.f / 4096.f);
            float tl = (float)(tau_d - (double)th12);
            // ZOH coefficient: C * B * (exp(dt*A)-1)/A, doubled for 2*Re()
            float s0, c0;
            __sincosf(6.28318530717958647692f * (float)tau_d, &s0, &c0);
            float er = __expf(dre);
            float2 ew = make_float2(er * c0, er * s0);
            float inv2 = 1.f / (are * are + aim * aim);
            float2 num = make_float2(ew.x - 1.f, ew.y);
            float2 disc = make_float2((num.x * are + num.y * aim) * inv2,
                                      (num.y * are - num.x * aim) * inv2);
            float2 Bc = make_float2(B_ri[2 * idx], B_ri[2 * idx + 1]);
            float2 CB = cmulf(Bc, disc);
            int i0 = (0 * Hn + h) * Nn + n, i1 = (1 * Hn + h) * Nn + n;
            float2 C0 = cmulf(make_float2(C_ri[2 * i0], C_ri[2 * i0 + 1]), CB);
            float2 C1 = cmulf(make_float2(C_ri[2 * i1], C_ri[2 * i1 + 1]), CB);
            C0.x *= 2.f; C0.y *= 2.f;
            C1.x *= 2.f; C1.y *= 2.f;
#pragma unroll
            for (int i = 0; i < 8; ++i) {
                float l = (float)(tid + NT * i);
                float ph = l * th12;
                ph -= floorf(ph);
                ph += l * tl;
                ph -= floorf(ph);
                float s, c;
                __sincosf(6.28318530717958647692f * ph, &s, &c);
                float e = __expf(dre * l);
                acc0[i] += e * (C0.x * c - C0.y * s);
                acc1[i] += e * (C1.x * c - C1.y * s);
            }
        }
        float* P = (hh == 0) ? ZR : ZI;
#pragma unroll
        for (int i = 0; i < 8; ++i) {
            int l = tid + NT * i;
            P[SWI(l)] = acc0[i];
            P[SWI(Mfft - 1 - l)] = acc1[i];
        }
    }
}

// ---------------- kernel 1: gen + FFT of the 256 channel-pairs -> KF spectra ----------------
__global__ __launch_bounds__(NT) void k_fftk(const float* __restrict__ log_dt,
                                             const float* __restrict__ lnA,
                                             const float* __restrict__ A_im,
                                             const float* __restrict__ B_ri,
                                             const float* __restrict__ C_ri,
                                             float2* __restrict__ KF) {
    __shared__ float ZR[Mfft];
    __shared__ float ZI[Mfft];
    int g = blockIdx.x, tid = threadIdx.x;
    gen_planes(ZR, ZI, g, tid, log_dt, lnA, A_im, B_ri, C_ri);
    fft_fwd(ZR, ZI, tid);
    const float scale = 1.f / (float)Mfft;  // irfft normalization folded in
    for (int k = tid; k <= Ln; k += NT) {
        int pk = pmap(k), pmk = pmap((Mfft - k) & (Mfft - 1));
        float2 zk = ldz(ZR, ZI, pk), zmk = ldz(ZR, ZI, pmk);
        float2 kf0 = make_float2(0.5f * (zk.x + zmk.x) * scale, 0.5f * (zk.y - zmk.y) * scale);
        float2 kf1 = make_float2(0.5f * (zk.y + zmk.y) * scale, -0.5f * (zk.x - zmk.x) * scale);
        KF[(size_t)(2 * g) * KFSTRIDE + k] = kf0;
        KF[(size_t)(2 * g + 1) * KFSTRIDE + k] = kf1;
    }
}

// ---------------- kernel 2: FFT convolution, 2 channels per WG ----------------
__global__ __launch_bounds__(NT, 4) void k_conv(const float* __restrict__ u,
                                                const float* __restrict__ D,
                                                const float2* __restrict__ KF,
                                                float* __restrict__ y) {
    __shared__ float ZR[Mfft];
    __shared__ float ZI[Mfft];
    int wg = blockIdx.x;
    int g = wg & 255, b = wg >> 8;  // same g -> same XCD (256 % 8 == 0): KF L2-resident per XCD
    int tid = threadIdx.x;
    int h0 = 2 * g, h1 = h0 + 1;
    const float* u0 = u + ((size_t)b * Hn + h0) * Ln;
    const float* u1 = u + ((size_t)b * Hn + h1) * Ln;
    float r0[8], r1[8];
#pragma unroll
    for (int i = 0; i < 8; ++i) {
        int l = tid + NT * i;
        r0[i] = u0[l];
        r1[i] = u1[l];
        int s_ = SWI(l);
        ZR[s_] = r0[i];
        ZI[s_] = r1[i];
        int s2 = SWI(l + Ln);
        ZR[s2] = 0.f;
        ZI[s2] = 0.f;
    }
    fft_fwd(ZR, ZI, tid);
    for (int k = tid; k <= Ln; k += NT) {
        int pk = pmap(k), pmk = pmap((Mfft - k) & (Mfft - 1));
        float2 zk = ldz(ZR, ZI, pk), zmk = ldz(ZR, ZI, pmk);
        float2 U0 = make_float2(0.5f * (zk.x + zmk.x), 0.5f * (zk.y - zmk.y));
        float2 U1 = make_float2(0.5f * (zk.y + zmk.y), -0.5f * (zk.x - zmk.x));
        float2 kf0 = KF[(size_t)h0 * KFSTRIDE + k];
        float2 kf1 = KF[(size_t)h1 * KFSTRIDE + k];
        float2 y0 = cmulf(U0, kf0);
        float2 y1 = cmulf(U1, kf1);
        stz(ZR, ZI, pk, make_float2(y0.x - y1.y, y0.y + y1.x));  // Y = y0 + i*y1
        if (k != 0 && k != Ln) {
            stz(ZR, ZI, pmk, make_float2(y0.x + y1.y, y1.x - y0.y));  // conj parts
        }
    }
    fft_inv(ZR, ZI, tid);
    float D0 = D[h0], D1 = D[h1];
    float* y0p = y + ((size_t)b * Hn + h0) * Ln;
    float* y1p = y + ((size_t)b * Hn + h1) * Ln;
#pragma unroll
    for (int i = 0; i < 8; ++i) {
        int l = tid + NT * i;
        float2 zl = ldz(ZR, ZI, l);
        y0p[l] = zl.x + D0 * r0[i];
        y1p[l] = zl.y + D1 * r1[i];
    }
}

// ---------------- fallback (no workspace): fully fused ----------------
__global__ __launch_bounds__(NT) void k_conv_fused(const float* __restrict__ u,
                                                   const float* __restrict__ log_dt,
                                                   const float* __restrict__ lnA,
                                                   const float* __restrict__ A_im,
                                                   const float* __restrict__ B_ri,
                                                   const float* __restrict__ C_ri,
                                                   const float* __restrict__ D,
                                                   float* __restrict__ y) {
    __shared__ float ZR[Mfft];
    __shared__ float ZI[Mfft];
    int wg = blockIdx.x;
    int g = wg & 255, b = wg >> 8;
    int tid = threadIdx.x;
    int h0 = 2 * g, h1 = h0 + 1;

    gen_planes(ZR, ZI, g, tid, log_dt, lnA, A_im, B_ri, C_ri);
    fft_fwd(ZR, ZI, tid);
    float2 kf0r[9], kf1r[9];
    const float scale = 1.f / (float)Mfft;
#pragma unroll
    for (int i = 0; i < 9; ++i) {
        int k = tid + NT * i;
        if (k <= Ln) {
            int pk = pmap(k), pmk = pmap((Mfft - k) & (Mfft - 1));
            float2 zk = ldz(ZR, ZI, pk), zmk = ldz(ZR, ZI, pmk);
            kf0r[i] = make_float2(0.5f * (zk.x + zmk.x) * scale, 0.5f * (zk.y - zmk.y) * scale);
            kf1r[i] = make_float2(0.5f * (zk.y + zmk.y) * scale, -0.5f * (zk.x - zmk.x) * scale);
        }
    }
    __syncthreads();

    const float* u0 = u + ((size_t)b * Hn + h0) * Ln;
    const float* u1 = u + ((size_t)b * Hn + h1) * Ln;
    float r0[8], r1[8];
#pragma unroll
    for (int i = 0; i < 8; ++i) {
        int l = tid + NT * i;
        r0[i] = u0[l];
        r1[i] = u1[l];
        int s_ = SWI(l);
        ZR[s_] = r0[i];
        ZI[s_] = r1[i];
        int s2 = SWI(l + Ln);
        ZR[s2] = 0.f;
        ZI[s2] = 0.f;
    }
    fft_fwd(ZR, ZI, tid);
#pragma unroll
    for (int i = 0; i < 9; ++i) {
        int k = tid + NT * i;
        if (k <= Ln) {
            int pk = pmap(k), pmk = pmap((Mfft - k) & (Mfft - 1));
            float2 zk = ldz(ZR, ZI, pk), zmk = ldz(ZR, ZI, pmk);
            float2 U0 = make_float2(0.5f * (zk.x + zmk.x), 0.5f * (zk.y - zmk.y));
            float2 U1 = make_float2(0.5f * (zk.y + zmk.y), -0.5f * (zk.x - zmk.x));
            float2 y0 = cmulf(U0, kf0r[i]);
            float2 y1 = cmulf(U1, kf1r[i]);
            stz(ZR, ZI, pk, make_float2(y0.x - y1.y, y0.y + y1.x));
            if (k != 0 && k != Ln) {
                stz(ZR, ZI, pmk, make_float2(y0.x + y1.y, y1.x - y0.y));
            }
        }
    }
    fft_inv(ZR, ZI, tid);
    float D0 = D[h0], D1 = D[h1];
    float* y0p = y + ((size_t)b * Hn + h0) * Ln;
    float* y1p = y + ((size_t)b * Hn + h1) * Ln;
#pragma unroll
    for (int i = 0; i < 8; ++i) {
        int l = tid + NT * i;
        float2 zl = ldz(ZR, ZI, l);
        y0p[l] = zl.x + D0 * r0[i];
        y1p[l] = zl.y + D1 * r1[i];
    }
}

extern "C" void kernel_launch(void* const* d_in, const int* in_sizes, int n_in,
                              void* d_out, int out_size, void* d_ws, size_t ws_size,
                              hipStream_t stream) {
    const float* u = (const float*)d_in[0];
    const float* log_dt = (const float*)d_in[1];
    const float* lnA = (const float*)d_in[2];
    const float* A_im = (const float*)d_in[3];
    const float* B_ri = (const float*)d_in[4];
    const float* C_ri = (const float*)d_in[5];
    const float* D = (const float*)d_in[6];
    float* y = (float*)d_out;

    const size_t kf_bytes = (size_t)Hn * KFSTRIDE * sizeof(float2);  // ~16.8 MB
    if (ws_size >= kf_bytes) {
        float2* KF = (float2*)d_ws;
        k_fftk<<<Hn / 2, NT, 0, stream>>>(log_dt, lnA, A_im, B_ri, C_ri, KF);
        k_conv<<<Bn * Hn / 2, NT, 0, stream>>>(u, D, KF, y);
    } else {
        k_conv_fused<<<Bn * Hn / 2, NT, 0, stream>>>(u, log_dt, lnA, A_im, B_ri, C_ri, D, y);
    }
}

// Round 3
// 215.398 us; speedup vs baseline: 1.5082x; 1.4653x over previous
//
#include <hip/hip_runtime.h>
#include <math.h>

#define Hn 512
#define Nn 32
#define Bn 8
#define Ln 4096
#define NF 4096            // complex FFT length (= 16^3)
#define NT 256             // threads per WG
#define ROWF 4097          // float2 stride per channel row in KF workspace
#define TWOPI 6.28318530717958647692f

// ---------------- complex helpers ----------------
__device__ __forceinline__ float2 cmulf(float2 a, float2 b) {
    return make_float2(a.x * b.x - a.y * b.y, a.x * b.y + a.y * b.x);
}
__device__ __forceinline__ float2 caddf(float2 a, float2 b) { return make_float2(a.x + b.x, a.y + b.y); }
__device__ __forceinline__ float2 csubf(float2 a, float2 b) { return make_float2(a.x - b.x, a.y - b.y); }

// LDS dword swizzle: verified conflict-free (<=2 lanes/bank) for all stage/pointwise patterns below
__device__ __forceinline__ int SW(int a) { return a ^ ((a >> 5) & 31); }
// storage position of frequency k after DIF stages stride 256, 16, 1
__device__ __forceinline__ int pos4(int k) { return ((k & 15) << 8) | (((k >> 4) & 15) << 4) | ((k >> 8) & 15); }

__device__ __forceinline__ float2 ldz(const float* ZR, const float* ZI, int a) {
    int s = SW(a);
    return make_float2(ZR[s], ZI[s]);
}
__device__ __forceinline__ void stz(float* ZR, float* ZI, int a, float2 v) {
    int s = SW(a);
    ZR[s] = v.x;
    ZI[s] = v.y;
}

// ---------------- in-register DFT-16 ----------------
template <int SGN>
__device__ __forceinline__ void dft4(float2& a0, float2& a1, float2& a2, float2& a3) {
    float2 t0 = caddf(a0, a2), t1 = csubf(a0, a2);
    float2 t2 = caddf(a1, a3), t3 = csubf(a1, a3);
    float2 it3 = (SGN < 0) ? make_float2(t3.y, -t3.x) : make_float2(-t3.y, t3.x);
    a0 = caddf(t0, t2);
    a2 = csubf(t0, t2);
    a1 = caddf(t1, it3);
    a3 = csubf(t1, it3);
}

// natural-order input; output freq r lands in x[sl(r)], sl(r)=((r&3)<<2)|(r>>2)
// ZTOP: inputs x[8..15] are known-zero (never read)
template <int SGN, bool ZTOP>
__device__ __forceinline__ void dft16(float2* x) {
    const float C1 = 0.92387953251128675613f, S1 = 0.38268343236508977173f, R2 = 0.70710678118654752440f;
    const float sg = (SGN < 0) ? -1.f : 1.f;
    if (ZTOP) {
#pragma unroll
        for (int q = 0; q < 4; ++q) {
            float2 xa = x[q], xb = x[q + 4];
            float2 it3 = (SGN < 0) ? make_float2(xb.y, -xb.x) : make_float2(-xb.y, xb.x);
            x[q] = caddf(xa, xb);
            x[q + 8] = csubf(xa, xb);
            x[q + 4] = caddf(xa, it3);
            x[q + 12] = csubf(xa, it3);
        }
    } else {
#pragma unroll
        for (int q = 0; q < 4; ++q) dft4<SGN>(x[q], x[q + 4], x[q + 8], x[q + 12]);
    }
    const float2 w1 = make_float2(C1, sg * S1);
    const float2 w2 = make_float2(R2, sg * R2);
    const float2 w3 = make_float2(S1, sg * C1);
    const float2 w6 = make_float2(-R2, sg * R2);
    const float2 w9 = make_float2(-C1, -sg * S1);
    x[5] = cmulf(x[5], w1);
    x[9] = cmulf(x[9], w2);
    x[13] = cmulf(x[13], w3);
    x[6] = cmulf(x[6], w2);
    x[10] = make_float2(-sg * x[10].y, sg * x[10].x);
    x[14] = cmulf(x[14], w6);
    x[7] = cmulf(x[7], w3);
    x[11] = cmulf(x[11], w6);
    x[15] = cmulf(x[15], w9);
#pragma unroll
    for (int a = 0; a < 4; ++a) dft4<SGN>(x[4 * a + 0], x[4 * a + 1], x[4 * a + 2], x[4 * a + 3]);
}

template <int SGN>
__device__ __forceinline__ void build_wr(float2* wr, float tau) {
    float s, c;
    __sincosf(TWOPI * tau, &s, &c);
    float2 w1 = make_float2(c, (SGN < 0) ? -s : s);
    wr[0] = make_float2(1.f, 0.f);
    wr[1] = w1;
    wr[2] = cmulf(w1, w1);
    wr[3] = cmulf(wr[2], w1);
    wr[4] = cmulf(wr[2], wr[2]);
    wr[5] = cmulf(wr[4], w1);
    wr[6] = cmulf(wr[4], wr[2]);
    wr[7] = cmulf(wr[4], wr[3]);
    wr[8] = cmulf(wr[4], wr[4]);
    wr[9] = cmulf(wr[8], w1);
    wr[10] = cmulf(wr[8], wr[2]);
    wr[11] = cmulf(wr[8], wr[3]);
    wr[12] = cmulf(wr[8], wr[4]);
    wr[13] = cmulf(wr[8], wr[5]);
    wr[14] = cmulf(wr[8], wr[6]);
    wr[15] = cmulf(wr[8], wr[7]);
}

// middle/last LDS stage. TW: apply stage twiddle (stage C has none)
template <int SGN, bool TW>
__device__ void stage_lds(float* ZR, float* ZI, int base, int stride, float tau) {
    float2 x[16];
#pragma unroll
    for (int p = 0; p < 16; ++p) x[p] = ldz(ZR, ZI, base + stride * p);
    if (SGN < 0) {
        dft16<SGN, false>(x);
        if (TW) {
            float2 wr[16];
            build_wr<SGN>(wr, tau);
            stz(ZR, ZI, base, x[0]);
#pragma unroll
            for (int r = 1; r < 16; ++r) {
                int sl = ((r & 3) << 2) | (r >> 2);
                stz(ZR, ZI, base + stride * r, cmulf(x[sl], wr[r]));
            }
        } else {
#pragma unroll
            for (int r = 0; r < 16; ++r) {
                int sl = ((r & 3) << 2) | (r >> 2);
                stz(ZR, ZI, base + stride * r, x[sl]);
            }
        }
    } else {
        if (TW) {
            float2 wr[16];
            build_wr<SGN>(wr, tau);
#pragma unroll
            for (int r = 1; r < 16; ++r) x[r] = cmulf(x[r], wr[r]);
        }
        dft16<SGN, false>(x);
#pragma unroll
        for (int n = 0; n < 16; ++n) {
            int sl = ((n & 3) << 2) | (n >> 2);
            stz(ZR, ZI, base + stride * n, x[sl]);
        }
    }
}

// forward stage A: dft16 already done by caller; apply w_4096^{j r} and scatter
__device__ __forceinline__ void scatterA(float* ZR, float* ZI, int j, float2* x) {
    float2 wr[16];
    build_wr<-1>(wr, (float)j * (1.f / 4096.f));
    stz(ZR, ZI, j, x[0]);
#pragma unroll
    for (int r = 1; r < 16; ++r) {
        int sl = ((r & 3) << 2) | (r >> 2);
        stz(ZR, ZI, j + 256 * r, cmulf(x[sl], wr[r]));
    }
}

// rfft untangle + kernel-multiply + irfft re-tangle for the pair (k, 4096-k), in place
__device__ __forceinline__ void pointwise_pair(float* ZR, float* ZI, int k, float2 KA, float2 KB) {
    int pk = pos4(k), pm = pos4((NF - k) & (NF - 1));
    float2 Xk = ldz(ZR, ZI, pk), Xm = ldz(ZR, ZI, pm);
    float2 E = make_float2(0.5f * (Xk.x + Xm.x), 0.5f * (Xk.y - Xm.y));
    float2 O = make_float2(0.5f * (Xk.y + Xm.y), -0.5f * (Xk.x - Xm.x));
    float s, c;
    __sincosf(-TWOPI * (float)k * (1.f / 8192.f), &s, &c);   // w = e^{-2pi i k/8192}
    float2 P = cmulf(make_float2(c, s), O);
    float2 Vk = caddf(E, P);
    float2 Vm = make_float2(E.x - P.x, -(E.y - P.y));        // conj(E - P)
    float2 Yk = cmulf(Vk, KA);
    float2 Ym = cmulf(Vm, KB);
    float2 Ze = make_float2(0.5f * (Yk.x + Ym.x), 0.5f * (Yk.y - Ym.y));
    float2 T = make_float2(0.5f * (Yk.x - Ym.x), 0.5f * (Yk.y + Ym.y));
    float2 Zo = make_float2(c * T.x + s * T.y, c * T.y - s * T.x);  // conj(w)*T
    stz(ZR, ZI, pk, make_float2(Ze.x - Zo.y, Ze.y + Zo.x));         // Ze + i Zo
    stz(ZR, ZI, pm, make_float2(Ze.x + Zo.y, -Ze.y + Zo.x));        // conj(Ze) + i conj(Zo)
}

// ---------------- kernel 1: per-channel kernel spectrum (D folded, 1/4096 folded) ----------------
__global__ __launch_bounds__(NT, 2) void k_fftk(const float* __restrict__ log_dt,
                                                const float* __restrict__ lnA,
                                                const float* __restrict__ A_im,
                                                const float* __restrict__ B_ri,
                                                const float* __restrict__ C_ri,
                                                const float* __restrict__ D,
                                                float2* __restrict__ KF) {
    __shared__ float ZR[NF];
    __shared__ float ZI[NF];
    __shared__ float CST[Nn][14];
    int h = blockIdx.x, j = threadIdx.x;
    if (j < Nn) {
        int n = j, idx = h * Nn + n;
        float dt = __expf(log_dt[h]);
        float are = -__expf(lnA[idx]);
        float aim = A_im[idx];
        float dre = dt * are;
        double taud = fmod((double)dt * (double)aim * 0.15915494309189533577, 1.0);
        if (taud < 0.0) taud += 1.0;
        float tau_hi = truncf((float)taud * 4096.f) * (1.f / 4096.f);
        float tau_lo = (float)(taud - (double)tau_hi);
        float s0, c0;
        __sincosf(TWOPI * (float)taud, &s0, &c0);
        float er = __expf(dre);
        float2 w = make_float2(er * c0, er * s0);               // e^{dt A}
        float inv2 = 1.f / (are * are + aim * aim);
        float2 num = make_float2(w.x - 1.f, w.y);
        float2 disc = make_float2((num.x * are + num.y * aim) * inv2,
                                  (num.y * are - num.x * aim) * inv2);   // (e^{dtA}-1)/A
        float2 Bc = make_float2(B_ri[2 * idx], B_ri[2 * idx + 1]);
        float2 CB = cmulf(Bc, disc);
        int i1 = Hn * Nn + idx;
        float2 cA = cmulf(make_float2(C_ri[2 * idx], C_ri[2 * idx + 1]), CB);
        cA.x *= 2.f; cA.y *= 2.f;
        float2 cC = cmulf(make_float2(C_ri[2 * i1], C_ri[2 * i1 + 1]), CB);
        cC.x *= 2.f; cC.y *= 2.f;
        float2 cB2 = cmulf(cA, w);
        float einv = __expf(-2.f * dre);
        float2 winv = make_float2(w.x * einv, -w.y * einv);      // w^{-1}
        float2 cD = cmulf(cC, winv);
        double t512 = fmod(512.0 * taud, 1.0);
        float e512 = __expf(512.f * dre);
        float sR, cR;
        __sincosf(TWOPI * (float)t512, &sR, &cR);
        CST[n][0] = cA.x;  CST[n][1] = cA.y;
        CST[n][2] = cB2.x; CST[n][3] = cB2.y;
        CST[n][4] = cC.x;  CST[n][5] = cC.y;
        CST[n][6] = cD.x;  CST[n][7] = cD.y;
        CST[n][8] = e512 * cR; CST[n][9] = e512 * sR;            // R512 = w^{512}
        CST[n][10] = dre; CST[n][11] = tau_hi; CST[n][12] = tau_lo;
    }
    __syncthreads();
    // gen packed time-domain kernel directly into stage-A registers:
    // x[p] = (K[2l], K[2l+1]) at l = j + 256 p ; l<2048: causal k0 ; l>=2048: k1 reversed
    float2 x[16];
#pragma unroll
    for (int p = 0; p < 16; ++p) x[p] = make_float2(0.f, 0.f);
    float l_lo = (float)(2 * j);
    float l_hi = (float)(511 - 2 * j);
    for (int n = 0; n < Nn; ++n) {
        float2 cA = make_float2(CST[n][0], CST[n][1]);
        float2 cB2 = make_float2(CST[n][2], CST[n][3]);
        float2 cC = make_float2(CST[n][4], CST[n][5]);
        float2 cD = make_float2(CST[n][6], CST[n][7]);
        float2 R = make_float2(CST[n][8], CST[n][9]);
        float dre = CST[n][10], thi = CST[n][11], tlo = CST[n][12];
        float ph = l_lo * thi;
        ph -= floorf(ph);
        ph += l_lo * tlo;
        ph -= floorf(ph);
        float s, c;
        __sincosf(TWOPI * ph, &s, &c);
        float m0 = __expf(dre * l_lo);
        float2 q = make_float2(m0 * c, m0 * s);                  // w^{2j}
#pragma unroll
        for (int p = 0; p < 8; ++p) {
            x[p].x += cA.x * q.x - cA.y * q.y;
            x[p].y += cB2.x * q.x - cB2.y * q.y;
            q = cmulf(q, R);
        }
        float ph2 = l_hi * thi;
        ph2 -= floorf(ph2);
        ph2 += l_hi * tlo;
        ph2 -= floorf(ph2);
        float s2, c2;
        __sincosf(TWOPI * ph2, &s2, &c2);
        float m1 = __expf(dre * l_hi);
        float2 r = make_float2(m1 * c2, m1 * s2);                // w^{511-2j}, decaying iteration
#pragma unroll
        for (int p = 15; p >= 8; --p) {
            x[p].x += cC.x * r.x - cC.y * r.y;
            x[p].y += cD.x * r.x - cD.y * r.y;
            r = cmulf(r, R);
        }
    }
    dft16<-1, false>(x);
    scatterA(ZR, ZI, j, x);
    __syncthreads();
    stage_lds<-1, true>(ZR, ZI, ((j >> 4) << 8) | (j & 15), 16, (float)(j & 15) * (1.f / 256.f));
    __syncthreads();
    stage_lds<-1, false>(ZR, ZI, j << 4, 1, 0.f);
    __syncthreads();
    // untangle to rfft bins; store in pointwise-permuted, coalesced layout; +D ; x 1/4096
    float Dh = D[h];
    const float inv = 1.f / 4096.f;
    float2* row = KF + (size_t)h * ROWF;
#pragma unroll
    for (int jj = 0; jj < 8; ++jj) {
        int k = ((j & 7) << 8) | (jj << 5) | (j >> 3);
        int pk = pos4(k), pm = pos4((NF - k) & (NF - 1));
        float2 Xk = ldz(ZR, ZI, pk), Xm = ldz(ZR, ZI, pm);
        float2 E = make_float2(0.5f * (Xk.x + Xm.x), 0.5f * (Xk.y - Xm.y));
        float2 O = make_float2(0.5f * (Xk.y + Xm.y), -0.5f * (Xk.x - Xm.x));
        float s, c;
        __sincosf(-TWOPI * (float)k * (1.f / 8192.f), &s, &c);
        float2 P = cmulf(make_float2(c, s), O);
        row[jj * 256 + j] = make_float2((E.x + P.x + Dh) * inv, (E.y + P.y) * inv);
        row[2048 + jj * 256 + j] = make_float2((E.x - P.x + Dh) * inv, -(E.y - P.y) * inv);
    }
    if (j == NT - 1) {  // bin k = 2048 (self-paired)
        float2 Xk = ldz(ZR, ZI, pos4(2048));
        row[4096] = make_float2((Xk.x + Dh) * inv, -Xk.y * inv);
    }
}

// ---------------- kernel 2: FFT convolution, one (batch,channel) per WG ----------------
__global__ __launch_bounds__(NT, 4) void k_conv(const float* __restrict__ u,
                                                const float2* __restrict__ KF,
                                                float* __restrict__ y) {
    __shared__ float ZR[NF];
    __shared__ float ZI[NF];
    int wg = blockIdx.x;
    int b = wg & 7, h = wg >> 3;   // 8 batches of a channel land on 8 XCDs; KF row L2/L3-shared
    int j = threadIdx.x;
    const float2* u2 = (const float2*)(u + ((size_t)b * Hn + h) * Ln);
    // forward stage A fused with load; upper half of padded input is zero
    float2 x[16];
#pragma unroll
    for (int p = 0; p < 8; ++p) x[p] = u2[j + 256 * p];
    dft16<-1, true>(x);
    scatterA(ZR, ZI, j, x);
    __syncthreads();
    stage_lds<-1, true>(ZR, ZI, ((j >> 4) << 8) | (j & 15), 16, (float)(j & 15) * (1.f / 256.f));
    __syncthreads();
    stage_lds<-1, false>(ZR, ZI, j << 4, 1, 0.f);
    __syncthreads();
    // pointwise multiply (rfft untangle -> *KF -> irfft tangle), permuted coalesced KF reads
    const float2* row = KF + (size_t)h * ROWF;
#pragma unroll
    for (int jj = 0; jj < 8; ++jj) {
        int k = ((j & 7) << 8) | (jj << 5) | (j >> 3);
        pointwise_pair(ZR, ZI, k, row[jj * 256 + j], row[2048 + jj * 256 + j]);
    }
    if (j == NT - 1) pointwise_pair(ZR, ZI, 2048, row[4096], row[4096]);
    __syncthreads();
    // inverse stages
    stage_lds<1, false>(ZR, ZI, j << 4, 1, 0.f);
    __syncthreads();
    stage_lds<1, true>(ZR, ZI, ((j >> 4) << 8) | (j & 15), 16, (float)(j & 15) * (1.f / 256.f));
    __syncthreads();
    // inverse stage A' fused with store; only first half of time outputs needed
    float2 xx[16];
#pragma unroll
    for (int p = 0; p < 16; ++p) xx[p] = ldz(ZR, ZI, j + 256 * p);
    {
        float2 wr[16];
        build_wr<1>(wr, (float)j * (1.f / 4096.f));
#pragma unroll
        for (int r = 1; r < 16; ++r) xx[r] = cmulf(xx[r], wr[r]);
    }
    dft16<1, false>(xx);
    float2* y2 = (float2*)(y + ((size_t)b * Hn + h) * Ln);
#pragma unroll
    for (int n = 0; n < 8; ++n) {
        int sl = ((n & 3) << 2) | (n >> 2);
        y2[j + 256 * n] = xx[sl];
    }
}

extern "C" void kernel_launch(void* const* d_in, const int* in_sizes, int n_in,
                              void* d_out, int out_size, void* d_ws, size_t ws_size,
                              hipStream_t stream) {
    const float* u = (const float*)d_in[0];
    const float* log_dt = (const float*)d_in[1];
    const float* lnA = (const float*)d_in[2];
    const float* A_im = (const float*)d_in[3];
    const float* B_ri = (const float*)d_in[4];
    const float* C_ri = (const float*)d_in[5];
    const float* D = (const float*)d_in[6];
    float* y = (float*)d_out;
    float2* KF = (float2*)d_ws;   // Hn * ROWF float2 = ~16.78 MB (fits: prior rounds used same)

    k_fftk<<<Hn, NT, 0, stream>>>(log_dt, lnA, A_im, B_ri, C_ri, D, KF);
    k_conv<<<Bn * Hn, NT, 0, stream>>>(u, KF, y);
}

// Round 5
// 188.844 us; speedup vs baseline: 1.7203x; 1.1406x over previous
//
#include <hip/hip_runtime.h>
#include <math.h>

#define Hn 512
#define Nn 32
#define Bn 8
#define Ln 4096
#define NF 4096            // complex FFT length (= 16^3)
#define NT 256             // threads per WG
#define ROWF 4097          // float2 stride per channel row in KF workspace
#define TWOPI 6.28318530717958647692f

// ---------------- complex helpers ----------------
__device__ __forceinline__ float2 cmulf(float2 a, float2 b) {
    return make_float2(a.x * b.x - a.y * b.y, a.x * b.y + a.y * b.x);
}
__device__ __forceinline__ float2 caddf(float2 a, float2 b) { return make_float2(a.x + b.x, a.y + b.y); }
__device__ __forceinline__ float2 csubf(float2 a, float2 b) { return make_float2(a.x - b.x, a.y - b.y); }

// LDS dword swizzle: conflict-free (<=2 lanes/bank) for all stage/pointwise patterns below
__device__ __forceinline__ int SW(int a) { return a ^ ((a >> 5) & 31); }
// storage position of frequency k after DIF stages stride 256, 16, 1
__device__ __forceinline__ int pos4(int k) { return ((k & 15) << 8) | (((k >> 4) & 15) << 4) | ((k >> 8) & 15); }

__device__ __forceinline__ float2 ldz(const float* ZR, const float* ZI, int a) {
    int s = SW(a);
    return make_float2(ZR[s], ZI[s]);
}
__device__ __forceinline__ void stz(float* ZR, float* ZI, int a, float2 v) {
    int s = SW(a);
    ZR[s] = v.x;
    ZI[s] = v.y;
}

// ---------------- in-register DFT-16 ----------------
template <int SGN>
__device__ __forceinline__ void dft4(float2& a0, float2& a1, float2& a2, float2& a3) {
    float2 t0 = caddf(a0, a2), t1 = csubf(a0, a2);
    float2 t2 = caddf(a1, a3), t3 = csubf(a1, a3);
    float2 it3 = (SGN < 0) ? make_float2(t3.y, -t3.x) : make_float2(-t3.y, t3.x);
    a0 = caddf(t0, t2);
    a2 = csubf(t0, t2);
    a1 = caddf(t1, it3);
    a3 = csubf(t1, it3);
}

// natural-order input; output freq r lands in x[sl(r)], sl(r)=((r&3)<<2)|(r>>2)
// ZTOP: inputs x[8..15] are known-zero (never read)
template <int SGN, bool ZTOP>
__device__ __forceinline__ void dft16(float2* x) {
    const float C1 = 0.92387953251128675613f, S1 = 0.38268343236508977173f, R2 = 0.70710678118654752440f;
    const float sg = (SGN < 0) ? -1.f : 1.f;
    if (ZTOP) {
#pragma unroll
        for (int q = 0; q < 4; ++q) {
            float2 xa = x[q], xb = x[q + 4];
            float2 it3 = (SGN < 0) ? make_float2(xb.y, -xb.x) : make_float2(-xb.y, xb.x);
            x[q] = caddf(xa, xb);
            x[q + 8] = csubf(xa, xb);
            x[q + 4] = caddf(xa, it3);
            x[q + 12] = csubf(xa, it3);
        }
    } else {
#pragma unroll
        for (int q = 0; q < 4; ++q) dft4<SGN>(x[q], x[q + 4], x[q + 8], x[q + 12]);
    }
    const float2 w1 = make_float2(C1, sg * S1);
    const float2 w2 = make_float2(R2, sg * R2);
    const float2 w3 = make_float2(S1, sg * C1);
    const float2 w6 = make_float2(-R2, sg * R2);
    const float2 w9 = make_float2(-C1, -sg * S1);
    x[5] = cmulf(x[5], w1);
    x[9] = cmulf(x[9], w2);
    x[13] = cmulf(x[13], w3);
    x[6] = cmulf(x[6], w2);
    x[10] = make_float2(-sg * x[10].y, sg * x[10].x);
    x[14] = cmulf(x[14], w6);
    x[7] = cmulf(x[7], w3);
    x[11] = cmulf(x[11], w6);
    x[15] = cmulf(x[15], w9);
#pragma unroll
    for (int a = 0; a < 4; ++a) dft4<SGN>(x[4 * a + 0], x[4 * a + 1], x[4 * a + 2], x[4 * a + 3]);
}

// middle/last LDS stage. TW: apply stage twiddle (last stage has none).
// Twiddles via running recurrence: ONE live float2 instead of a 16-entry table.
template <int SGN, bool TW>
__device__ void stage_lds(float* ZR, float* ZI, int base, int stride, float tau) {
    float2 x[16];
#pragma unroll
    for (int p = 0; p < 16; ++p) x[p] = ldz(ZR, ZI, base + stride * p);
    if (SGN < 0) {
        dft16<SGN, false>(x);
        if (TW) {
            float s, c;
            __sincosf(TWOPI * tau, &s, &c);
            float2 w1 = make_float2(c, -s);
            float2 w = w1;
            stz(ZR, ZI, base, x[0]);
#pragma unroll
            for (int r = 1; r < 16; ++r) {
                int sl = ((r & 3) << 2) | (r >> 2);
                stz(ZR, ZI, base + stride * r, cmulf(x[sl], w));
                w = cmulf(w, w1);
            }
        } else {
#pragma unroll
            for (int r = 0; r < 16; ++r) {
                int sl = ((r & 3) << 2) | (r >> 2);
                stz(ZR, ZI, base + stride * r, x[sl]);
            }
        }
    } else {
        if (TW) {
            float s, c;
            __sincosf(TWOPI * tau, &s, &c);
            float2 w1 = make_float2(c, s);
            float2 w = w1;
#pragma unroll
            for (int r = 1; r < 16; ++r) {
                x[r] = cmulf(x[r], w);
                w = cmulf(w, w1);
            }
        }
        dft16<SGN, false>(x);
#pragma unroll
        for (int n = 0; n < 16; ++n) {
            int sl = ((n & 3) << 2) | (n >> 2);
            stz(ZR, ZI, base + stride * n, x[sl]);
        }
    }
}

// forward stage A: dft16 already done by caller; apply w_4096^{j r} (running) and scatter
__device__ __forceinline__ void scatterA(float* ZR, float* ZI, int j, float2* x) {
    float s, c;
    __sincosf(TWOPI * (float)j * (1.f / 4096.f), &s, &c);
    float2 w1 = make_float2(c, -s);
    float2 w = w1;
    stz(ZR, ZI, j, x[0]);
#pragma unroll
    for (int r = 1; r < 16; ++r) {
        int sl = ((r & 3) << 2) | (r >> 2);
        stz(ZR, ZI, j + 256 * r, cmulf(x[sl], w));
        w = cmulf(w, w1);
    }
}

// rfft untangle + kernel-multiply + irfft re-tangle for the pair (k, 4096-k), in place
__device__ __forceinline__ void pointwise_pair(float* ZR, float* ZI, int k, float2 KA, float2 KB) {
    int pk = pos4(k), pm = pos4((NF - k) & (NF - 1));
    float2 Xk = ldz(ZR, ZI, pk), Xm = ldz(ZR, ZI, pm);
    float2 E = make_float2(0.5f * (Xk.x + Xm.x), 0.5f * (Xk.y - Xm.y));
    float2 O = make_float2(0.5f * (Xk.y + Xm.y), -0.5f * (Xk.x - Xm.x));
    float s, c;
    __sincosf(-TWOPI * (float)k * (1.f / 8192.f), &s, &c);   // w = e^{-2pi i k/8192}
    float2 P = cmulf(make_float2(c, s), O);
    float2 Vk = caddf(E, P);
    float2 Vm = make_float2(E.x - P.x, -(E.y - P.y));        // conj(E - P)
    float2 Yk = cmulf(Vk, KA);
    float2 Ym = cmulf(Vm, KB);
    float2 Ze = make_float2(0.5f * (Yk.x + Ym.x), 0.5f * (Yk.y - Ym.y));
    float2 T = make_float2(0.5f * (Yk.x - Ym.x), 0.5f * (Yk.y + Ym.y));
    float2 Zo = make_float2(c * T.x + s * T.y, c * T.y - s * T.x);  // conj(w)*T
    stz(ZR, ZI, pk, make_float2(Ze.x - Zo.y, Ze.y + Zo.x));         // Ze + i Zo
    stz(ZR, ZI, pm, make_float2(Ze.x + Zo.y, -Ze.y + Zo.x));        // conj(Ze) + i conj(Zo)
}

// ---------------- kernel 1: per-channel kernel spectrum (D folded, 1/4096 folded) ----------------
__global__ __launch_bounds__(NT, 2) void k_fftk(const float* __restrict__ log_dt,
                                                const float* __restrict__ lnA,
                                                const float* __restrict__ A_im,
                                                const float* __restrict__ B_ri,
                                                const float* __restrict__ C_ri,
                                                const float* __restrict__ D,
                                                float2* __restrict__ KF) {
    __shared__ float ZR[NF];
    __shared__ float ZI[NF];
    __shared__ float CST[Nn][14];
    int h = blockIdx.x, j = threadIdx.x;
    if (j < Nn) {
        int n = j, idx = h * Nn + n;
        float dt = __expf(log_dt[h]);
        float are = -__expf(lnA[idx]);
        float aim = A_im[idx];
        float dre = dt * are;
        double taud = fmod((double)dt * (double)aim * 0.15915494309189533577, 1.0);
        if (taud < 0.0) taud += 1.0;
        float tau_hi = truncf((float)taud * 4096.f) * (1.f / 4096.f);
        float tau_lo = (float)(taud - (double)tau_hi);
        float s0, c0;
        __sincosf(TWOPI * (float)taud, &s0, &c0);
        float er = __expf(dre);
        float2 w = make_float2(er * c0, er * s0);               // e^{dt A}
        float inv2 = 1.f / (are * are + aim * aim);
        float2 num = make_float2(w.x - 1.f, w.y);
        float2 disc = make_float2((num.x * are + num.y * aim) * inv2,
                                  (num.y * are - num.x * aim) * inv2);   // (e^{dtA}-1)/A
        float2 Bc = make_float2(B_ri[2 * idx], B_ri[2 * idx + 1]);
        float2 CB = cmulf(Bc, disc);
        int i1 = Hn * Nn + idx;
        float2 cA = cmulf(make_float2(C_ri[2 * idx], C_ri[2 * idx + 1]), CB);
        cA.x *= 2.f; cA.y *= 2.f;
        float2 cC = cmulf(make_float2(C_ri[2 * i1], C_ri[2 * i1 + 1]), CB);
        cC.x *= 2.f; cC.y *= 2.f;
        float2 cB2 = cmulf(cA, w);
        float einv = __expf(-2.f * dre);
        float2 winv = make_float2(w.x * einv, -w.y * einv);      // w^{-1}
        float2 cD = cmulf(cC, winv);
        double t512 = fmod(512.0 * taud, 1.0);
        float e512 = __expf(512.f * dre);
        float sR, cR;
        __sincosf(TWOPI * (float)t512, &sR, &cR);
        CST[n][0] = cA.x;  CST[n][1] = cA.y;
        CST[n][2] = cB2.x; CST[n][3] = cB2.y;
        CST[n][4] = cC.x;  CST[n][5] = cC.y;
        CST[n][6] = cD.x;  CST[n][7] = cD.y;
        CST[n][8] = e512 * cR; CST[n][9] = e512 * sR;            // R512 = w^{512}
        CST[n][10] = dre; CST[n][11] = tau_hi; CST[n][12] = tau_lo;
    }
    __syncthreads();
    // gen packed time-domain kernel: x[p] = (K[2l], K[2l+1]) at l = j + 256 p.
    // Two passes of 8 accumulators each (register-pressure control); pass-lo results are
    // parked in this thread's own ZR/ZI slots (thread-private, no barrier needed).
    {   // pass lo: p = 0..7 (causal direction)
        float2 acc[8];
#pragma unroll
        for (int p = 0; p < 8; ++p) acc[p] = make_float2(0.f, 0.f);
        float l_lo = (float)(2 * j);
        for (int n = 0; n < Nn; ++n) {
            float2 cA = make_float2(CST[n][0], CST[n][1]);
            float2 cB2 = make_float2(CST[n][2], CST[n][3]);
            float2 R = make_float2(CST[n][8], CST[n][9]);
            float dre = CST[n][10], thi = CST[n][11], tlo = CST[n][12];
            float ph = l_lo * thi;
            ph -= floorf(ph);
            ph += l_lo * tlo;
            ph -= floorf(ph);
            float s, c;
            __sincosf(TWOPI * ph, &s, &c);
            float m0 = __expf(dre * l_lo);
            float2 q = make_float2(m0 * c, m0 * s);              // w^{2j}
#pragma unroll
            for (int p = 0; p < 8; ++p) {
                acc[p].x += cA.x * q.x - cA.y * q.y;
                acc[p].y += cB2.x * q.x - cB2.y * q.y;
                q = cmulf(q, R);
            }
        }
#pragma unroll
        for (int p = 0; p < 8; ++p) stz(ZR, ZI, j + 256 * p, acc[p]);   // park
    }
    float2 x[16];
    {   // pass hi: p = 8..15 (anticausal direction, reversed; decaying iteration)
        float2 acc[8];
#pragma unroll
        for (int p = 0; p < 8; ++p) acc[p] = make_float2(0.f, 0.f);
        float l_hi = (float)(511 - 2 * j);
        for (int n = 0; n < Nn; ++n) {
            float2 cC = make_float2(CST[n][4], CST[n][5]);
            float2 cD = make_float2(CST[n][6], CST[n][7]);
            float2 R = make_float2(CST[n][8], CST[n][9]);
            float dre = CST[n][10], thi = CST[n][11], tlo = CST[n][12];
            float ph2 = l_hi * thi;
            ph2 -= floorf(ph2);
            ph2 += l_hi * tlo;
            ph2 -= floorf(ph2);
            float s2, c2;
            __sincosf(TWOPI * ph2, &s2, &c2);
            float m1 = __expf(dre * l_hi);
            float2 r = make_float2(m1 * c2, m1 * s2);            // w^{511-2j}
#pragma unroll
            for (int p = 7; p >= 0; --p) {
                acc[p].x += cC.x * r.x - cC.y * r.y;
                acc[p].y += cD.x * r.x - cD.y * r.y;
                r = cmulf(r, R);
            }
        }
#pragma unroll
        for (int p = 0; p < 8; ++p) x[8 + p] = acc[p];
    }
#pragma unroll
    for (int p = 0; p < 8; ++p) x[p] = ldz(ZR, ZI, j + 256 * p);        // unpark
    dft16<-1, false>(x);
    scatterA(ZR, ZI, j, x);   // overwrites this thread's own slots only; consumed already
    __syncthreads();
    stage_lds<-1, true>(ZR, ZI, ((j >> 4) << 8) | (j & 15), 16, (float)(j & 15) * (1.f / 256.f));
    __syncthreads();
    stage_lds<-1, false>(ZR, ZI, j << 4, 1, 0.f);
    __syncthreads();
    // untangle to rfft bins; store in pointwise-permuted, coalesced layout; +D ; x 1/4096
    float Dh = D[h];
    const float inv = 1.f / 4096.f;
    float2* row = KF + (size_t)h * ROWF;
#pragma unroll
    for (int jj = 0; jj < 8; ++jj) {
        int k = ((j & 7) << 8) | (jj << 5) | (j >> 3);
        int pk = pos4(k), pm = pos4((NF - k) & (NF - 1));
        float2 Xk = ldz(ZR, ZI, pk), Xm = ldz(ZR, ZI, pm);
        float2 E = make_float2(0.5f * (Xk.x + Xm.x), 0.5f * (Xk.y - Xm.y));
        float2 O = make_float2(0.5f * (Xk.y + Xm.y), -0.5f * (Xk.x - Xm.x));
        float s, c;
        __sincosf(-TWOPI * (float)k * (1.f / 8192.f), &s, &c);
        float2 P = cmulf(make_float2(c, s), O);
        row[jj * 256 + j] = make_float2((E.x + P.x + Dh) * inv, (E.y + P.y) * inv);
        row[2048 + jj * 256 + j] = make_float2((E.x - P.x + Dh) * inv, -(E.y - P.y) * inv);
    }
    if (j == NT - 1) {  // bin k = 2048 (self-paired)
        float2 Xk = ldz(ZR, ZI, pos4(2048));
        row[4096] = make_float2((Xk.x + Dh) * inv, -Xk.y * inv);
    }
}

// ---------------- kernel 2: FFT convolution, one (batch,channel) per WG ----------------
__global__ __launch_bounds__(NT, 4) void k_conv(const float* __restrict__ u,
                                                const float2* __restrict__ KF,
                                                float* __restrict__ y) {
    __shared__ float ZR[NF];
    __shared__ float ZI[NF];
    int wg = blockIdx.x;
    int h = wg & 511, b = wg >> 9;   // same h -> same XCD (h%8 == wg%8): KF row stays in XCD L2
    int j = threadIdx.x;
    const float2* u2 = (const float2*)(u + ((size_t)b * Hn + h) * Ln);
    // forward stage A fused with load; upper half of padded input is zero
    float2 x[16];
#pragma unroll
    for (int p = 0; p < 8; ++p) x[p] = u2[j + 256 * p];
    dft16<-1, true>(x);
    scatterA(ZR, ZI, j, x);
    __syncthreads();
    stage_lds<-1, true>(ZR, ZI, ((j >> 4) << 8) | (j & 15), 16, (float)(j & 15) * (1.f / 256.f));
    __syncthreads();
    stage_lds<-1, false>(ZR, ZI, j << 4, 1, 0.f);
    __syncthreads();
    // pointwise multiply (rfft untangle -> *KF -> irfft tangle), permuted coalesced KF reads
    const float2* row = KF + (size_t)h * ROWF;
#pragma unroll
    for (int jj = 0; jj < 8; ++jj) {
        int k = ((j & 7) << 8) | (jj << 5) | (j >> 3);
        pointwise_pair(ZR, ZI, k, row[jj * 256 + j], row[2048 + jj * 256 + j]);
    }
    if (j == NT - 1) pointwise_pair(ZR, ZI, 2048, row[4096], row[4096]);
    __syncthreads();
    // inverse stages
    stage_lds<1, false>(ZR, ZI, j << 4, 1, 0.f);
    __syncthreads();
    stage_lds<1, true>(ZR, ZI, ((j >> 4) << 8) | (j & 15), 16, (float)(j & 15) * (1.f / 256.f));
    __syncthreads();
    // inverse stage A' fused with store; only first half of time outputs needed
    float2 xx[16];
#pragma unroll
    for (int p = 0; p < 16; ++p) xx[p] = ldz(ZR, ZI, j + 256 * p);
    {
        float s, c;
        __sincosf(TWOPI * (float)j * (1.f / 4096.f), &s, &c);
        float2 w1 = make_float2(c, s);
        float2 w = w1;
#pragma unroll
        for (int r = 1; r < 16; ++r) {
            xx[r] = cmulf(xx[r], w);
            w = cmulf(w, w1);
        }
    }
    dft16<1, false>(xx);
    float2* y2 = (float2*)(y + ((size_t)b * Hn + h) * Ln);
#pragma unroll
    for (int n = 0; n < 8; ++n) {
        int sl = ((n & 3) << 2) | (n >> 2);
        y2[j + 256 * n] = xx[sl];
    }
}

extern "C" void kernel_launch(void* const* d_in, const int* in_sizes, int n_in,
                              void* d_out, int out_size, void* d_ws, size_t ws_size,
                              hipStream_t stream) {
    const float* u = (const float*)d_in[0];
    const float* log_dt = (const float*)d_in[1];
    const float* lnA = (const float*)d_in[2];
    const float* A_im = (const float*)d_in[3];
    const float* B_ri = (const float*)d_in[4];
    const float* C_ri = (const float*)d_in[5];
    const float* D = (const float*)d_in[6];
    float* y = (float*)d_out;
    float2* KF = (float2*)d_ws;   // Hn * ROWF float2 = ~16.78 MB

    k_fftk<<<Hn, NT, 0, stream>>>(log_dt, lnA, A_im, B_ri, C_ri, D, KF);
    k_conv<<<Bn * Hn, NT, 0, stream>>>(u, KF, y);
}